// Round 4
// baseline (398.518 us; speedup 1.0000x reference)
//
#include <hip/hip_runtime.h>

// EdgeConv fused pipeline, MI355X gfx950 — round 4.
// R3 post-mortem: VGPR=232 -> 9.6% occupancy; latency-bound gather with no
// waves to hide it. R4: xj gather goes global->LDS via global_load_lds
// (no staging VGPRs), 3 nodes in flight per wave with exact vmcnt discipline,
// XOR-swizzled chunk placement so A-frag ds_read_b128 is ~conflict-free.
// pass1 capped at 170 VGPR (3 waves/SIMD), pass2 at 256 (2 waves/SIMD).

#define N_NODES 100000
#define KE 16
#define E_EDGES (N_NODES * KE)
#define BN_EPS 1e-5f
#define NCHUNK (N_NODES / KE)      // 6250 16-node wave-chunks (exact)
#define PASS_BLOCKS ((NCHUNK + 3) / 4)

typedef __attribute__((ext_vector_type(8))) short bf16x8;  // 8 bf16 (4 VGPRs)
typedef __attribute__((ext_vector_type(4))) float f32x4;   // MFMA C/D
typedef __attribute__((ext_vector_type(4))) int i32x4;

#define MFMA(a, b, c) __builtin_amdgcn_mfma_f32_16x16x32_bf16((a), (b), (c), 0, 0, 0)

static __device__ __forceinline__ short bf16b(float f) {
  __bf16 h = (__bf16)f;  // RNE, hardware cvt on gfx950
  return __builtin_bit_cast(short, h);
}

#if __has_builtin(__builtin_amdgcn_cvt_pk_bf16_f32)
static __device__ __forceinline__ int pk2(float a, float b) {
  return __builtin_bit_cast(int, __builtin_amdgcn_cvt_pk_bf16_f32(a, b));
}
#else
static __device__ __forceinline__ int pk2(float a, float b) {
  return (int)(unsigned short)bf16b(a) | ((int)(unsigned short)bf16b(b) << 16);
}
#endif

static __device__ __forceinline__ bf16x8 pack8(float4 a, float4 b) {
  i32x4 v = {pk2(a.x, a.y), pk2(a.z, a.w), pk2(b.x, b.y), pk2(b.z, b.w)};
  return __builtin_bit_cast(bf16x8, v);
}

static __device__ __forceinline__ float bf2f(short s) {
  unsigned u = ((unsigned)(unsigned short)s) << 16;
  return __builtin_bit_cast(float, u);
}

// global (AS1) -> LDS (AS3) direct 16B/lane load; LDS dst is wave-uniform
// base + lane*16 (hard constraint of the instruction).
static __device__ __forceinline__ void glds16(const short* g, short* lds) {
  __builtin_amdgcn_global_load_lds((const __attribute__((address_space(1))) void*)g,
                                   (__attribute__((address_space(3))) void*)lds,
                                   16, 0, 0);
}

// ---- x -> bf16 (one-time; 12.8 MB result stays L2/L3-resident) -------------
__global__ __launch_bounds__(256) void k_cvt(const float* __restrict__ x,
                                             short* __restrict__ xb) {
  int g = blockIdx.x * 256 + threadIdx.x;  // 800000 threads, 8 elems each
  const float4* x4 = (const float4*)x;
  float4 f0 = x4[2 * g], f1 = x4[2 * g + 1];
  bf16x8 v = pack8(f0, f1);
  *(bf16x8*)(xb + g * 8) = v;
}

// ---- weight packing into MFMA B-fragment order -----------------------------
// wp[(s*4+t)*64 + l] holds 8 bf16: B[k=32s + (l>>4)*8 + j][c=16t + (l&15)]
// Weight split: k-steps 0,1 (xi operand) get Wd = W1[:64]-W1[64:]; k-steps
// 2,3 (xj operand) get Wb = W1[64:]. Then no xj-xi subtraction is needed.
__global__ void pack_w(const float* __restrict__ W1, const float* __restrict__ W2,
                       short* __restrict__ wp1, short* __restrict__ wp2) {
  int tid = blockIdx.x * blockDim.x + threadIdx.x;
  if (tid < 1024) {
    int l = tid & 63, st = tid >> 6;
    int s = st >> 2, t = st & 3;
    int quad = l >> 4, n16 = l & 15;
    for (int j = 0; j < 8; j++) {
      int k = 32 * s + quad * 8 + j, c = 16 * t + n16;
      float w = (s < 2) ? (W1[k * 64 + c] - W1[(k + 64) * 64 + c])
                        : W1[k * 64 + c];
      wp1[tid * 8 + j] = bf16b(w);
    }
  } else if (tid < 1536) {
    int e = tid - 1024;
    int l = e & 63, st = e >> 6;
    int s = st >> 2, t = st & 3;
    int quad = l >> 4, n16 = l & 15;
    for (int j = 0; j < 8; j++) {
      int k = 32 * s + quad * 8 + j, c = 16 * t + n16;
      wp2[e * 8 + j] = bf16b(W2[k * 64 + c]);
    }
  }
}

// ---- stats helpers ---------------------------------------------------------
static __device__ __forceinline__ void stat_acc(const f32x4 acc[4], float sacc[4],
                                                float qacc[4]) {
#pragma unroll
  for (int t = 0; t < 4; t++) {
    sacc[t] += (acc[t][0] + acc[t][1]) + (acc[t][2] + acc[t][3]);
    qacc[t] = fmaf(acc[t][0], acc[t][0],
              fmaf(acc[t][1], acc[t][1],
              fmaf(acc[t][2], acc[t][2],
              fmaf(acc[t][3], acc[t][3], qacc[t]))));
  }
}

static __device__ __forceinline__ void stat_flush(float sacc[4], float qacc[4],
                                                  int quad, int n16, float* lstat) {
#pragma unroll
  for (int t = 0; t < 4; t++) {
    float s = sacc[t], q = qacc[t];
    s += __shfl_xor(s, 16); s += __shfl_xor(s, 32);
    q += __shfl_xor(q, 16); q += __shfl_xor(q, 32);
    if (quad == 0) {
      atomicAdd(&lstat[16 * t + n16], s);
      atomicAdd(&lstat[64 + 16 * t + n16], q);
    }
  }
}

// Swizzled A-frag read from a gathered 16x64 bf16 LDS tile.
// Producer put global chunk c of row r at chunk-position c^(r&7); consumer
// lane (n16,quad) needs chunks quad and 4+quad of row n16.
static __device__ __forceinline__ bf16x8 tile_rd(const short* tile, int row,
                                                 int chunk) {
  return *(const bf16x8*)(tile + row * 64 + (((chunk) ^ (row & 7)) << 3));
}

// ---- pass 1: LDS-gather + GEMM1 + stats1 ----------------------------------
__global__ __launch_bounds__(256, 3) void k_pass1(const short* __restrict__ xb,
                                                  const int* __restrict__ ecol,
                                                  const bf16x8* __restrict__ wp1,
                                                  float* __restrict__ gacc) {
  __shared__ float lstat[128];
  __shared__ int eblk[4][256];
  __shared__ __align__(16) short xjs[4][4][1024];  // 4 waves x 4 slots x 2KB
  __shared__ __align__(16) short xit[4][1024];     // xi tiles (16 rows)
  int tid = threadIdx.x;
  if (tid < 128) lstat[tid] = 0.f;
  __syncthreads();
  int wave = tid >> 6, l = tid & 63, quad = l >> 4, n16 = l & 15;
  int r8 = l >> 3, cch = (l & 7) ^ r8;  // producer-side XOR swizzle
  bf16x8 wf[16];
#pragma unroll
  for (int u = 0; u < 16; u++) wf[u] = wp1[u * 64 + l];
  float sacc[4] = {0.f, 0.f, 0.f, 0.f}, qacc[4] = {0.f, 0.f, 0.f, 0.f};
  int w = blockIdx.x * 4 + wave;
  if (w < NCHUNK) {
    int nb = w * 16;
    int* eb = &eblk[wave][0];
    ((int4*)eb)[l] = ((const int4*)ecol)[(size_t)w * 64 + l];
    asm volatile("s_waitcnt vmcnt(0)" ::: "memory");  // exact counts from here
    glds16(xb + (size_t)(nb + r8) * 64 + cch * 8, &xit[wave][0]);
    glds16(xb + (size_t)(nb + 8 + r8) * 64 + cch * 8, &xit[wave][512]);
#pragma unroll
    for (int p = 0; p < 3; p++) {
      glds16(xb + (size_t)eb[p * 16 + r8] * 64 + cch * 8, &xjs[wave][p][0]);
      glds16(xb + (size_t)eb[p * 16 + 8 + r8] * 64 + cch * 8, &xjs[wave][p][512]);
    }
#pragma unroll
    for (int i = 0; i < 16; i++) {
      // outstanding here: i==0: XI(2)+J0..J2(6); i>0: J_{i+1..i+3}(6).
      asm volatile("s_waitcnt vmcnt(4)" ::: "memory");  // node i's data ready
      const short* xj = &xjs[wave][i & 3][0];
      bf16x8 xi0 = tile_rd(&xit[wave][0], i, quad);
      bf16x8 xi1 = tile_rd(&xit[wave][0], i, 4 + quad);
      bf16x8 xj0 = tile_rd(xj, n16, quad);
      bf16x8 xj1 = tile_rd(xj, n16, 4 + quad);
      f32x4 acc[4];
#pragma unroll
      for (int t = 0; t < 4; t++) {
        f32x4 a = {0.f, 0.f, 0.f, 0.f};
        a = MFMA(xi0, wf[0 + t], a);
        a = MFMA(xi1, wf[4 + t], a);
        a = MFMA(xj0, wf[8 + t], a);
        a = MFMA(xj1, wf[12 + t], a);
        acc[t] = a;
      }
      stat_acc(acc, sacc, qacc);
      asm volatile("" ::: "memory");  // keep next issue below the ds_reads
      int ii = (i + 3 <= 15) ? i + 3 : 15;  // clamped re-issues are harmless
      glds16(xb + (size_t)eb[ii * 16 + r8] * 64 + cch * 8, &xjs[wave][(i + 3) & 3][0]);
      glds16(xb + (size_t)eb[ii * 16 + 8 + r8] * 64 + cch * 8, &xjs[wave][(i + 3) & 3][512]);
    }
  }
  stat_flush(sacc, qacc, quad, n16, lstat);
  __syncthreads();
  if (tid < 128) atomicAdd(&gacc[(blockIdx.x & 63) * 128 + tid], lstat[tid]);
}

// ---- BN stats finalize -----------------------------------------------------
__global__ void k_finalize(const float* __restrict__ gacc, const float* __restrict__ g,
                           const float* __restrict__ be, float* __restrict__ bn) {
  int c = threadIdx.x;  // 64 threads
  float s = 0.f, q = 0.f;
  for (int i = 0; i < 64; i++) {
    s += gacc[i * 128 + c];
    q += gacc[i * 128 + 64 + c];
  }
  float mean = s * (1.0f / E_EDGES);
  float var = q * (1.0f / E_EDGES) - mean * mean;  // biased, matches reference
  float rstd = rsqrtf(var + BN_EPS);
  float a = g[c] * rstd;
  bn[c] = a;
  bn[64 + c] = be[c] - mean * a;  // bn(v) = v*a + b
}

// ---- pass 2: LDS-gather + GEMM1 + BN1/ReLU + GEMM2 + stats2 + node min/max -
__global__ __launch_bounds__(256, 2) void k_pass2(const short* __restrict__ xb,
                                                  const int* __restrict__ ecol,
                                                  const bf16x8* __restrict__ wp1,
                                                  const bf16x8* __restrict__ wp2,
                                                  const float* __restrict__ bn1,
                                                  float* __restrict__ gacc,
                                                  short* __restrict__ hmax,
                                                  short* __restrict__ hmin) {
  __shared__ float lstat[128];
  __shared__ int eblk[4][256];
  __shared__ __align__(16) short xjs[4][4][1024];
  __shared__ __align__(16) short xit[4][1024];
  __shared__ __align__(16) short tiles[4][16 * 72];  // D->A transpose, stride 72
  int tid = threadIdx.x;
  if (tid < 128) lstat[tid] = 0.f;
  __syncthreads();
  int wave = tid >> 6, l = tid & 63, quad = l >> 4, n16 = l & 15;
  int r8 = l >> 3, cch = (l & 7) ^ r8;
  bf16x8 wf1[16], wf2[8];
#pragma unroll
  for (int u = 0; u < 16; u++) wf1[u] = wp1[u * 64 + l];
#pragma unroll
  for (int u = 0; u < 8; u++) wf2[u] = wp2[u * 64 + l];
  float a1c[4], b1c[4];
#pragma unroll
  for (int t = 0; t < 4; t++) {
    a1c[t] = bn1[16 * t + n16];
    b1c[t] = bn1[64 + 16 * t + n16];
  }
  float sacc[4] = {0.f, 0.f, 0.f, 0.f}, qacc[4] = {0.f, 0.f, 0.f, 0.f};
  short* myt = &tiles[wave][0];
  int w = blockIdx.x * 4 + wave;
  if (w < NCHUNK) {
    int nb = w * 16;
    int* eb = &eblk[wave][0];
    ((int4*)eb)[l] = ((const int4*)ecol)[(size_t)w * 64 + l];
    asm volatile("s_waitcnt vmcnt(0)" ::: "memory");
    glds16(xb + (size_t)(nb + r8) * 64 + cch * 8, &xit[wave][0]);
    glds16(xb + (size_t)(nb + 8 + r8) * 64 + cch * 8, &xit[wave][512]);
#pragma unroll
    for (int p = 0; p < 3; p++) {
      glds16(xb + (size_t)eb[p * 16 + r8] * 64 + cch * 8, &xjs[wave][p][0]);
      glds16(xb + (size_t)eb[p * 16 + 8 + r8] * 64 + cch * 8, &xjs[wave][p][512]);
    }
#pragma unroll
    for (int i = 0; i < 16; i++) {
      // i==0: outstanding = XI(2)+J0..J2(6) -> wait(4) completes XI+J0.
      // i>=1: outstanding = J_{i+1},J_{i+2},st_{i-1},J_{i+3} (8) -> wait(6)
      //       completes exactly J_{i+1} (stores never block).
      if (i == 0) asm volatile("s_waitcnt vmcnt(4)" ::: "memory");
      else        asm volatile("s_waitcnt vmcnt(6)" ::: "memory");
      const short* xj = &xjs[wave][i & 3][0];
      bf16x8 xi0 = tile_rd(&xit[wave][0], i, quad);
      bf16x8 xi1 = tile_rd(&xit[wave][0], i, 4 + quad);
      bf16x8 xj0 = tile_rd(xj, n16, quad);
      bf16x8 xj1 = tile_rd(xj, n16, 4 + quad);
      f32x4 acc1[4];
#pragma unroll
      for (int t = 0; t < 4; t++) {
        f32x4 a = {0.f, 0.f, 0.f, 0.f};
        a = MFMA(xi0, wf1[0 + t], a);
        a = MFMA(xi1, wf1[4 + t], a);
        a = MFMA(xj0, wf1[8 + t], a);
        a = MFMA(xj1, wf1[12 + t], a);
        acc1[t] = a;
      }
      // BN1 + ReLU, D-layout -> row-major bf16 tile (per-wave, no barrier)
#pragma unroll
      for (int t = 0; t < 4; t++) {
        int c = 16 * t + n16;
#pragma unroll
        for (int r = 0; r < 4; r++) {
          float h = fmaxf(fmaf(acc1[t][r], a1c[t], b1c[t]), 0.f);
          myt[(quad * 4 + r) * 72 + c] = bf16b(h);
        }
      }
      bf16x8 f0 = *(bf16x8*)(myt + n16 * 72 + quad * 8);
      bf16x8 f1 = *(bf16x8*)(myt + n16 * 72 + 32 + quad * 8);
      f32x4 acc2[4];
#pragma unroll
      for (int t = 0; t < 4; t++) {
        f32x4 a = {0.f, 0.f, 0.f, 0.f};
        a = MFMA(f0, wf2[0 + t], a);
        a = MFMA(f1, wf2[4 + t], a);
        acc2[t] = a;
      }
      stat_acc(acc2, sacc, qacc);
      // per-node, per-channel max & min of h2_pre over the 16 edges
      float vmx[4], vmn[4];
#pragma unroll
      for (int t = 0; t < 4; t++) {
        float mx = fmaxf(fmaxf(acc2[t][0], acc2[t][1]), fmaxf(acc2[t][2], acc2[t][3]));
        float mn = fminf(fminf(acc2[t][0], acc2[t][1]), fminf(acc2[t][2], acc2[t][3]));
        mx = fmaxf(mx, __shfl_xor(mx, 16)); mx = fmaxf(mx, __shfl_xor(mx, 32));
        mn = fminf(mn, __shfl_xor(mn, 16)); mn = fminf(mn, __shfl_xor(mn, 32));
        vmx[t] = mx; vmn[t] = mn;
      }
      int n = nb + i;
      float ox = (quad == 0) ? vmx[0] : (quad == 1) ? vmx[1] : (quad == 2) ? vmx[2] : vmx[3];
      float on = (quad == 0) ? vmn[0] : (quad == 1) ? vmn[1] : (quad == 2) ? vmn[2] : vmn[3];
      hmax[(size_t)n * 64 + l] = bf16b(ox);  // 2 store ops per iteration
      hmin[(size_t)n * 64 + l] = bf16b(on);
      asm volatile("" ::: "memory");  // keep next issue below reads/stores
      int ii = (i + 3 <= 15) ? i + 3 : 15;
      glds16(xb + (size_t)eb[ii * 16 + r8] * 64 + cch * 8, &xjs[wave][(i + 3) & 3][0]);
      glds16(xb + (size_t)eb[ii * 16 + 8 + r8] * 64 + cch * 8, &xjs[wave][(i + 3) & 3][512]);
    }
  }
  stat_flush(sacc, qacc, quad, n16, lstat);
  __syncthreads();
  if (tid < 128) atomicAdd(&gacc[(blockIdx.x & 63) * 128 + tid], lstat[tid]);
}

// ---- pass 3: elementwise BN2 + ReLU + sign-select of stored min/max --------
// max_m relu(a*h+b) = relu(a>=0 ? a*hmax+b : a*hmin+b)  (affine+relu monotone)
__global__ __launch_bounds__(256) void k_pass3(const short* __restrict__ hmax,
                                               const short* __restrict__ hmin,
                                               const float* __restrict__ bn2,
                                               float* __restrict__ out) {
  int g = blockIdx.x * 256 + threadIdx.x;  // 1.6M threads, 4 channels each
  int base = g * 4;
  int c4 = base & 63;
  short4 mx4 = *(const short4*)(hmax + base);
  short4 mn4 = *(const short4*)(hmin + base);
  float4 a4 = *(const float4*)(bn2 + c4);
  float4 b4 = *(const float4*)(bn2 + 64 + c4);
  float4 o;
  o.x = fmaxf(a4.x >= 0.f ? fmaf(a4.x, bf2f(mx4.x), b4.x) : fmaf(a4.x, bf2f(mn4.x), b4.x), 0.f);
  o.y = fmaxf(a4.y >= 0.f ? fmaf(a4.y, bf2f(mx4.y), b4.y) : fmaf(a4.y, bf2f(mn4.y), b4.y), 0.f);
  o.z = fmaxf(a4.z >= 0.f ? fmaf(a4.z, bf2f(mx4.z), b4.z) : fmaf(a4.z, bf2f(mn4.z), b4.z), 0.f);
  o.w = fmaxf(a4.w >= 0.f ? fmaf(a4.w, bf2f(mx4.w), b4.w) : fmaf(a4.w, bf2f(mn4.w), b4.w), 0.f);
  *(float4*)(out + base) = o;
}

extern "C" void kernel_launch(void* const* d_in, const int* in_sizes, int n_in,
                              void* d_out, int out_size, void* d_ws, size_t ws_size,
                              hipStream_t stream) {
  const float* x   = (const float*)d_in[0];
  // d_in[1] = edge_row: structurally repeat(arange(N),16), unused
  const int*   ec  = (const int*)d_in[2];
  const float* W1  = (const float*)d_in[3];
  // d_in[4] = b1: cancels in BN, unused
  const float* g1  = (const float*)d_in[5];
  const float* be1 = (const float*)d_in[6];
  const float* W2  = (const float*)d_in[7];
  // d_in[8] = b2: cancels in BN, unused
  const float* g2  = (const float*)d_in[9];
  const float* be2 = (const float*)d_in[10];
  float* out = (float*)d_out;

  char* ws = (char*)d_ws;
  bf16x8* wp1  = (bf16x8*)(ws);                 // 16 KB packed W1 (split)
  bf16x8* wp2  = (bf16x8*)(ws + 16384);         // 8 KB packed W2
  float* gacc1 = (float*)(ws + 24576);          // 64 slots x 128 = 32 KB
  float* gacc2 = (float*)(ws + 57344);          // 32 KB
  float* bn1   = (float*)(ws + 90112);          // a[64], b[64]
  float* bn2   = (float*)(ws + 90624);
  short* xb    = (short*)(ws + 98304);          // x in bf16: 12.8 MB
  short* hmax  = (short*)(ws + 98304 + 12800000);         // 12.8 MB
  short* hmin  = (short*)(ws + 98304 + 2 * 12800000);     // 12.8 MB

  // ws is re-poisoned to 0xAA before every launch: zero the stat accumulators
  hipMemsetAsync(gacc1, 0, 65536, stream);

  hipLaunchKernelGGL(pack_w, dim3(6), dim3(256), 0, stream, W1, W2,
                     (short*)wp1, (short*)wp2);
  hipLaunchKernelGGL(k_cvt, dim3(3125), dim3(256), 0, stream, x, xb);
  hipLaunchKernelGGL(k_pass1, dim3(PASS_BLOCKS), dim3(256), 0, stream,
                     xb, ec, wp1, gacc1);
  hipLaunchKernelGGL(k_finalize, dim3(1), dim3(64), 0, stream, gacc1, g1, be1, bn1);
  hipLaunchKernelGGL(k_pass2, dim3(PASS_BLOCKS), dim3(256), 0, stream,
                     xb, ec, wp1, wp2, bn1, gacc2, hmax, hmin);
  hipLaunchKernelGGL(k_finalize, dim3(1), dim3(64), 0, stream, gacc2, g2, be2, bn2);
  hipLaunchKernelGGL(k_pass3, dim3(6250), dim3(256), 0, stream, hmax, hmin, bn2, out);
}

// Round 5
// 378.843 us; speedup vs baseline: 1.0519x; 1.0519x over previous
//
#include <hip/hip_runtime.h>

// EdgeConv fused pipeline, MI355X gfx950 — round 5.
// R4 post-mortem: global_load_lds gathers = 100% L2 miss (FETCH == request
// bytes) -> HBM-BW-bound. R3 post-mortem (revised): SA=SB stage copies forced
// vmcnt waits on the *next* node's loads -> pipeline depth ~1.
// R5: VGPR gathers (cache-allocating) + copy-free 4-deep rotating stage array
// (static indices, in-order vmcnt retirement keeps 3 nodes in flight while
// consuming one). xi tile via LDS (1 contiguous 2KB load/chunk). pass1
// (256,3) ~12 waves/CU; pass2 (256,2) with 4-deep pipe = 32 nodes/CU in flight.

#define N_NODES 100000
#define KE 16
#define E_EDGES (N_NODES * KE)
#define BN_EPS 1e-5f
#define NCHUNK (N_NODES / KE)      // 6250 16-node wave-chunks (exact)
#define PASS_BLOCKS ((NCHUNK + 3) / 4)

typedef __attribute__((ext_vector_type(8))) short bf16x8;  // 8 bf16 (4 VGPRs)
typedef __attribute__((ext_vector_type(4))) float f32x4;   // MFMA C/D
typedef __attribute__((ext_vector_type(4))) int i32x4;

#define MFMA(a, b, c) __builtin_amdgcn_mfma_f32_16x16x32_bf16((a), (b), (c), 0, 0, 0)

static __device__ __forceinline__ short bf16b(float f) {
  __bf16 h = (__bf16)f;  // RNE, hardware cvt on gfx950
  return __builtin_bit_cast(short, h);
}

#if __has_builtin(__builtin_amdgcn_cvt_pk_bf16_f32)
static __device__ __forceinline__ int pk2(float a, float b) {
  return __builtin_bit_cast(int, __builtin_amdgcn_cvt_pk_bf16_f32(a, b));
}
#else
static __device__ __forceinline__ int pk2(float a, float b) {
  return (int)(unsigned short)bf16b(a) | ((int)(unsigned short)bf16b(b) << 16);
}
#endif

static __device__ __forceinline__ bf16x8 pack8(float4 a, float4 b) {
  i32x4 v = {pk2(a.x, a.y), pk2(a.z, a.w), pk2(b.x, b.y), pk2(b.z, b.w)};
  return __builtin_bit_cast(bf16x8, v);
}

static __device__ __forceinline__ float bf2f(short s) {
  unsigned u = ((unsigned)(unsigned short)s) << 16;
  return __builtin_bit_cast(float, u);
}

// ---- x -> bf16 (one-time; 12.8 MB result is the gather working set) --------
__global__ __launch_bounds__(256) void k_cvt(const float* __restrict__ x,
                                             short* __restrict__ xb) {
  int g = blockIdx.x * 256 + threadIdx.x;  // 800000 threads, 8 elems each
  const float4* x4 = (const float4*)x;
  float4 f0 = x4[2 * g], f1 = x4[2 * g + 1];
  bf16x8 v = pack8(f0, f1);
  *(bf16x8*)(xb + g * 8) = v;
}

// ---- weight packing into MFMA B-fragment order -----------------------------
// wp[(s*4+t)*64 + l] holds 8 bf16: B[k=32s + (l>>4)*8 + j][c=16t + (l&15)]
// Weight split: k-steps 0,1 (xi operand) get Wd = W1[:64]-W1[64:]; k-steps
// 2,3 (xj operand) get Wb = W1[64:]. Then no xj-xi subtraction is needed.
__global__ void pack_w(const float* __restrict__ W1, const float* __restrict__ W2,
                       short* __restrict__ wp1, short* __restrict__ wp2) {
  int tid = blockIdx.x * blockDim.x + threadIdx.x;
  if (tid < 1024) {
    int l = tid & 63, st = tid >> 6;
    int s = st >> 2, t = st & 3;
    int quad = l >> 4, n16 = l & 15;
    for (int j = 0; j < 8; j++) {
      int k = 32 * s + quad * 8 + j, c = 16 * t + n16;
      float w = (s < 2) ? (W1[k * 64 + c] - W1[(k + 64) * 64 + c])
                        : W1[k * 64 + c];
      wp1[tid * 8 + j] = bf16b(w);
    }
  } else if (tid < 1536) {
    int e = tid - 1024;
    int l = e & 63, st = e >> 6;
    int s = st >> 2, t = st & 3;
    int quad = l >> 4, n16 = l & 15;
    for (int j = 0; j < 8; j++) {
      int k = 32 * s + quad * 8 + j, c = 16 * t + n16;
      wp2[e * 8 + j] = bf16b(W2[k * 64 + c]);
    }
  }
}

// ---- stats helpers ---------------------------------------------------------
static __device__ __forceinline__ void stat_acc(const f32x4 acc[4], float sacc[4],
                                                float qacc[4]) {
#pragma unroll
  for (int t = 0; t < 4; t++) {
    sacc[t] += (acc[t][0] + acc[t][1]) + (acc[t][2] + acc[t][3]);
    qacc[t] = fmaf(acc[t][0], acc[t][0],
              fmaf(acc[t][1], acc[t][1],
              fmaf(acc[t][2], acc[t][2],
              fmaf(acc[t][3], acc[t][3], qacc[t]))));
  }
}

static __device__ __forceinline__ void stat_flush(float sacc[4], float qacc[4],
                                                  int quad, int n16, float* lstat) {
#pragma unroll
  for (int t = 0; t < 4; t++) {
    float s = sacc[t], q = qacc[t];
    s += __shfl_xor(s, 16); s += __shfl_xor(s, 32);
    q += __shfl_xor(q, 16); q += __shfl_xor(q, 32);
    if (quad == 0) {
      atomicAdd(&lstat[16 * t + n16], s);
      atomicAdd(&lstat[64 + 16 * t + n16], q);
    }
  }
}

// ---- pass 1: pipelined gather + GEMM1 + stats1 -----------------------------
__global__ __launch_bounds__(256, 3) void k_pass1(const short* __restrict__ xb,
                                                  const int* __restrict__ ecol,
                                                  const bf16x8* __restrict__ wp1,
                                                  float* __restrict__ gacc) {
  __shared__ float lstat[128];
  __shared__ int eblk[4][256];
  __shared__ __align__(16) short xit[4][1024];
  int tid = threadIdx.x;
  if (tid < 128) lstat[tid] = 0.f;
  __syncthreads();
  int wave = tid >> 6, l = tid & 63, quad = l >> 4, n16 = l & 15;
  bf16x8 wf[16];
#pragma unroll
  for (int u = 0; u < 16; u++) wf[u] = wp1[u * 64 + l];
  float sacc[4] = {0.f, 0.f, 0.f, 0.f}, qacc[4] = {0.f, 0.f, 0.f, 0.f};
  int w = blockIdx.x * 4 + wave;
  if (w < NCHUNK) {
    int nb = w * 16;
    int* eb = &eblk[wave][0];
    ((int4*)eb)[l] = ((const int4*)ecol)[(size_t)w * 64 + l];  // 256 idx -> LDS
    // xi tile: 16 contiguous rows (2KB) -> LDS, one coalesced pass
    const bf16x8* xsrc = (const bf16x8*)(xb + (size_t)nb * 64);
    bf16x8 xa = xsrc[2 * l], xc = xsrc[2 * l + 1];
    *(bf16x8*)(&xit[wave][l * 16]) = xa;
    *(bf16x8*)(&xit[wave][l * 16 + 8]) = xc;
    // 4-deep rotating xj pipeline — NO stage copies (static indices)
    bf16x8 sj0[4], sj1[4];
#pragma unroll
    for (int p = 0; p < 4; p++) {
      const short* pj = xb + (size_t)eb[p * 16 + n16] * 64 + quad * 8;
      sj0[p] = *(const bf16x8*)pj;
      sj1[p] = *(const bf16x8*)(pj + 32);
    }
#pragma unroll
    for (int i = 0; i < 16; i++) {
      bf16x8 xi0 = *(const bf16x8*)(&xit[wave][i * 64 + quad * 8]);
      bf16x8 xi1 = *(const bf16x8*)(&xit[wave][i * 64 + 32 + quad * 8]);
      f32x4 acc[4];
#pragma unroll
      for (int t = 0; t < 4; t++) {
        f32x4 a = {0.f, 0.f, 0.f, 0.f};
        a = MFMA(xi0, wf[0 + t], a);
        a = MFMA(xi1, wf[4 + t], a);
        a = MFMA(sj0[i & 3], wf[8 + t], a);
        a = MFMA(sj1[i & 3], wf[12 + t], a);
        acc[t] = a;
      }
      stat_acc(acc, sacc, qacc);
      if (i + 4 < 16) {  // refill just-freed stage (3 nodes stay in flight)
        const short* pj = xb + (size_t)eb[(i + 4) * 16 + n16] * 64 + quad * 8;
        sj0[i & 3] = *(const bf16x8*)pj;
        sj1[i & 3] = *(const bf16x8*)(pj + 32);
      }
    }
  }
  stat_flush(sacc, qacc, quad, n16, lstat);
  __syncthreads();
  if (tid < 128) atomicAdd(&gacc[(blockIdx.x & 63) * 128 + tid], lstat[tid]);
}

// ---- BN stats finalize -----------------------------------------------------
__global__ void k_finalize(const float* __restrict__ gacc, const float* __restrict__ g,
                           const float* __restrict__ be, float* __restrict__ bn) {
  int c = threadIdx.x;  // 64 threads
  float s = 0.f, q = 0.f;
  for (int i = 0; i < 64; i++) {
    s += gacc[i * 128 + c];
    q += gacc[i * 128 + 64 + c];
  }
  float mean = s * (1.0f / E_EDGES);
  float var = q * (1.0f / E_EDGES) - mean * mean;  // biased, matches reference
  float rstd = rsqrtf(var + BN_EPS);
  float a = g[c] * rstd;
  bn[c] = a;
  bn[64 + c] = be[c] - mean * a;  // bn(v) = v*a + b
}

// ---- pass 2: pipelined gather + GEMM1 + BN1/ReLU + GEMM2 + stats2 + min/max
__global__ __launch_bounds__(256, 2) void k_pass2(const short* __restrict__ xb,
                                                  const int* __restrict__ ecol,
                                                  const bf16x8* __restrict__ wp1,
                                                  const bf16x8* __restrict__ wp2,
                                                  const float* __restrict__ bn1,
                                                  float* __restrict__ gacc,
                                                  short* __restrict__ hmax,
                                                  short* __restrict__ hmin) {
  __shared__ float lstat[128];
  __shared__ int eblk[4][256];
  __shared__ __align__(16) short xit[4][1024];
  __shared__ __align__(16) short tiles[4][16 * 72];  // D->A transpose, stride 72
  int tid = threadIdx.x;
  if (tid < 128) lstat[tid] = 0.f;
  __syncthreads();
  int wave = tid >> 6, l = tid & 63, quad = l >> 4, n16 = l & 15;
  bf16x8 wf1[16], wf2[8];
#pragma unroll
  for (int u = 0; u < 16; u++) wf1[u] = wp1[u * 64 + l];
#pragma unroll
  for (int u = 0; u < 8; u++) wf2[u] = wp2[u * 64 + l];
  float a1c[4], b1c[4];
#pragma unroll
  for (int t = 0; t < 4; t++) {
    a1c[t] = bn1[16 * t + n16];
    b1c[t] = bn1[64 + 16 * t + n16];
  }
  float sacc[4] = {0.f, 0.f, 0.f, 0.f}, qacc[4] = {0.f, 0.f, 0.f, 0.f};
  short* myt = &tiles[wave][0];
  int w = blockIdx.x * 4 + wave;
  if (w < NCHUNK) {
    int nb = w * 16;
    int* eb = &eblk[wave][0];
    ((int4*)eb)[l] = ((const int4*)ecol)[(size_t)w * 64 + l];
    const bf16x8* xsrc = (const bf16x8*)(xb + (size_t)nb * 64);
    bf16x8 xa = xsrc[2 * l], xc = xsrc[2 * l + 1];
    *(bf16x8*)(&xit[wave][l * 16]) = xa;
    *(bf16x8*)(&xit[wave][l * 16 + 8]) = xc;
    bf16x8 sj0[4], sj1[4];
#pragma unroll
    for (int p = 0; p < 4; p++) {
      const short* pj = xb + (size_t)eb[p * 16 + n16] * 64 + quad * 8;
      sj0[p] = *(const bf16x8*)pj;
      sj1[p] = *(const bf16x8*)(pj + 32);
    }
#pragma unroll
    for (int i = 0; i < 16; i++) {
      bf16x8 xi0 = *(const bf16x8*)(&xit[wave][i * 64 + quad * 8]);
      bf16x8 xi1 = *(const bf16x8*)(&xit[wave][i * 64 + 32 + quad * 8]);
      f32x4 acc1[4];
#pragma unroll
      for (int t = 0; t < 4; t++) {
        f32x4 a = {0.f, 0.f, 0.f, 0.f};
        a = MFMA(xi0, wf1[0 + t], a);
        a = MFMA(xi1, wf1[4 + t], a);
        a = MFMA(sj0[i & 3], wf1[8 + t], a);
        a = MFMA(sj1[i & 3], wf1[12 + t], a);
        acc1[t] = a;
      }
      if (i + 4 < 16) {  // refill freed stage before the long tail of work
        const short* pj = xb + (size_t)eb[(i + 4) * 16 + n16] * 64 + quad * 8;
        sj0[i & 3] = *(const bf16x8*)pj;
        sj1[i & 3] = *(const bf16x8*)(pj + 32);
      }
      // BN1 + ReLU, D-layout -> row-major bf16 tile (per-wave, no barrier)
#pragma unroll
      for (int t = 0; t < 4; t++) {
        int c = 16 * t + n16;
#pragma unroll
        for (int r = 0; r < 4; r++) {
          float h = fmaxf(fmaf(acc1[t][r], a1c[t], b1c[t]), 0.f);
          myt[(quad * 4 + r) * 72 + c] = bf16b(h);
        }
      }
      bf16x8 f0 = *(bf16x8*)(myt + n16 * 72 + quad * 8);
      bf16x8 f1 = *(bf16x8*)(myt + n16 * 72 + 32 + quad * 8);
      f32x4 acc2[4];
#pragma unroll
      for (int t = 0; t < 4; t++) {
        f32x4 a = {0.f, 0.f, 0.f, 0.f};
        a = MFMA(f0, wf2[0 + t], a);
        a = MFMA(f1, wf2[4 + t], a);
        acc2[t] = a;
      }
      stat_acc(acc2, sacc, qacc);
      // per-node, per-channel max & min of h2_pre over the 16 edges
      float vmx[4], vmn[4];
#pragma unroll
      for (int t = 0; t < 4; t++) {
        float mx = fmaxf(fmaxf(acc2[t][0], acc2[t][1]), fmaxf(acc2[t][2], acc2[t][3]));
        float mn = fminf(fminf(acc2[t][0], acc2[t][1]), fminf(acc2[t][2], acc2[t][3]));
        mx = fmaxf(mx, __shfl_xor(mx, 16)); mx = fmaxf(mx, __shfl_xor(mx, 32));
        mn = fminf(mn, __shfl_xor(mn, 16)); mn = fminf(mn, __shfl_xor(mn, 32));
        vmx[t] = mx; vmn[t] = mn;
      }
      int n = nb + i;
      float ox = (quad == 0) ? vmx[0] : (quad == 1) ? vmx[1] : (quad == 2) ? vmx[2] : vmx[3];
      float on = (quad == 0) ? vmn[0] : (quad == 1) ? vmn[1] : (quad == 2) ? vmn[2] : vmn[3];
      hmax[(size_t)n * 64 + l] = bf16b(ox);  // lane l == channel l: coalesced
      hmin[(size_t)n * 64 + l] = bf16b(on);
    }
  }
  stat_flush(sacc, qacc, quad, n16, lstat);
  __syncthreads();
  if (tid < 128) atomicAdd(&gacc[(blockIdx.x & 63) * 128 + tid], lstat[tid]);
}

// ---- pass 3: elementwise BN2 + ReLU + sign-select of stored min/max --------
// max_m relu(a*h+b) = relu(a>=0 ? a*hmax+b : a*hmin+b)  (affine+relu monotone)
__global__ __launch_bounds__(256) void k_pass3(const short* __restrict__ hmax,
                                               const short* __restrict__ hmin,
                                               const float* __restrict__ bn2,
                                               float* __restrict__ out) {
  int g = blockIdx.x * 256 + threadIdx.x;  // 1.6M threads, 4 channels each
  int base = g * 4;
  int c4 = base & 63;
  short4 mx4 = *(const short4*)(hmax + base);
  short4 mn4 = *(const short4*)(hmin + base);
  float4 a4 = *(const float4*)(bn2 + c4);
  float4 b4 = *(const float4*)(bn2 + 64 + c4);
  float4 o;
  o.x = fmaxf(a4.x >= 0.f ? fmaf(a4.x, bf2f(mx4.x), b4.x) : fmaf(a4.x, bf2f(mn4.x), b4.x), 0.f);
  o.y = fmaxf(a4.y >= 0.f ? fmaf(a4.y, bf2f(mx4.y), b4.y) : fmaf(a4.y, bf2f(mn4.y), b4.y), 0.f);
  o.z = fmaxf(a4.z >= 0.f ? fmaf(a4.z, bf2f(mx4.z), b4.z) : fmaf(a4.z, bf2f(mn4.z), b4.z), 0.f);
  o.w = fmaxf(a4.w >= 0.f ? fmaf(a4.w, bf2f(mx4.w), b4.w) : fmaf(a4.w, bf2f(mn4.w), b4.w), 0.f);
  *(float4*)(out + base) = o;
}

extern "C" void kernel_launch(void* const* d_in, const int* in_sizes, int n_in,
                              void* d_out, int out_size, void* d_ws, size_t ws_size,
                              hipStream_t stream) {
  const float* x   = (const float*)d_in[0];
  // d_in[1] = edge_row: structurally repeat(arange(N),16), unused
  const int*   ec  = (const int*)d_in[2];
  const float* W1  = (const float*)d_in[3];
  // d_in[4] = b1: cancels in BN, unused
  const float* g1  = (const float*)d_in[5];
  const float* be1 = (const float*)d_in[6];
  const float* W2  = (const float*)d_in[7];
  // d_in[8] = b2: cancels in BN, unused
  const float* g2  = (const float*)d_in[9];
  const float* be2 = (const float*)d_in[10];
  float* out = (float*)d_out;

  char* ws = (char*)d_ws;
  bf16x8* wp1  = (bf16x8*)(ws);                 // 16 KB packed W1 (split)
  bf16x8* wp2  = (bf16x8*)(ws + 16384);         // 8 KB packed W2
  float* gacc1 = (float*)(ws + 24576);          // 64 slots x 128 = 32 KB
  float* gacc2 = (float*)(ws + 57344);          // 32 KB
  float* bn1   = (float*)(ws + 90112);          // a[64], b[64]
  float* bn2   = (float*)(ws + 90624);
  short* xb    = (short*)(ws + 98304);          // x in bf16: 12.8 MB
  short* hmax  = (short*)(ws + 98304 + 12800000);         // 12.8 MB
  short* hmin  = (short*)(ws + 98304 + 2 * 12800000);     // 12.8 MB

  // ws is re-poisoned to 0xAA before every launch: zero the stat accumulators
  hipMemsetAsync(gacc1, 0, 65536, stream);

  hipLaunchKernelGGL(pack_w, dim3(6), dim3(256), 0, stream, W1, W2,
                     (short*)wp1, (short*)wp2);
  hipLaunchKernelGGL(k_cvt, dim3(3125), dim3(256), 0, stream, x, xb);
  hipLaunchKernelGGL(k_pass1, dim3(PASS_BLOCKS), dim3(256), 0, stream,
                     xb, ec, wp1, gacc1);
  hipLaunchKernelGGL(k_finalize, dim3(1), dim3(64), 0, stream, gacc1, g1, be1, bn1);
  hipLaunchKernelGGL(k_pass2, dim3(PASS_BLOCKS), dim3(256), 0, stream,
                     xb, ec, wp1, wp2, bn1, gacc2, hmax, hmin);
  hipLaunchKernelGGL(k_finalize, dim3(1), dim3(64), 0, stream, gacc2, g2, be2, bn2);
  hipLaunchKernelGGL(k_pass3, dim3(6250), dim3(256), 0, stream, hmax, hmin, bn2, out);
}

// Round 6
// 245.834 us; speedup vs baseline: 1.6211x; 1.5410x over previous
//
#include <hip/hip_runtime.h>

// EdgeConv fused pipeline, MI355X gfx950 — round 6.
// R5 post-mortem: pass1 dur invariant under pipeline restructure (149 vs 150);
// VGPR was only 84, occupancy 26% (grid 1563 = 6 blocks/CU ceiling + serial
// 16-node loop -> too few concurrent gather streams). Counters for pass1 are
// contaminated by harness restore traffic (~308 MB phantom WRITE).
// R6: one wave = 4 nodes, all 8 gather loads issued up-front (no rotation, no
// asm); grid 6250 (4x blocks); W1 fragments staged in LDS (frees 64 VGPRs) ->
// high occupancy = many concurrent gather streams. pass1 (256,4), pass2 (256,3).

#define N_NODES 100000
#define KE 16
#define E_EDGES (N_NODES * KE)
#define BN_EPS 1e-5f
#define NCHUNK (N_NODES / KE)      // 6250 16-node block-chunks (exact)

typedef __attribute__((ext_vector_type(8))) short bf16x8;  // 8 bf16 (4 VGPRs)
typedef __attribute__((ext_vector_type(4))) float f32x4;   // MFMA C/D
typedef __attribute__((ext_vector_type(4))) int i32x4;

#define MFMA(a, b, c) __builtin_amdgcn_mfma_f32_16x16x32_bf16((a), (b), (c), 0, 0, 0)

static __device__ __forceinline__ short bf16b(float f) {
  __bf16 h = (__bf16)f;  // RNE, hardware cvt on gfx950
  return __builtin_bit_cast(short, h);
}

#if __has_builtin(__builtin_amdgcn_cvt_pk_bf16_f32)
static __device__ __forceinline__ int pk2(float a, float b) {
  return __builtin_bit_cast(int, __builtin_amdgcn_cvt_pk_bf16_f32(a, b));
}
#else
static __device__ __forceinline__ int pk2(float a, float b) {
  return (int)(unsigned short)bf16b(a) | ((int)(unsigned short)bf16b(b) << 16);
}
#endif

static __device__ __forceinline__ bf16x8 pack8(float4 a, float4 b) {
  i32x4 v = {pk2(a.x, a.y), pk2(a.z, a.w), pk2(b.x, b.y), pk2(b.z, b.w)};
  return __builtin_bit_cast(bf16x8, v);
}

static __device__ __forceinline__ float bf2f(short s) {
  unsigned u = ((unsigned)(unsigned short)s) << 16;
  return __builtin_bit_cast(float, u);
}

// ---- x -> bf16 (one-time; 12.8 MB result is the gather working set) --------
__global__ __launch_bounds__(256) void k_cvt(const float* __restrict__ x,
                                             short* __restrict__ xb) {
  int g = blockIdx.x * 256 + threadIdx.x;  // 800000 threads, 8 elems each
  const float4* x4 = (const float4*)x;
  float4 f0 = x4[2 * g], f1 = x4[2 * g + 1];
  bf16x8 v = pack8(f0, f1);
  *(bf16x8*)(xb + g * 8) = v;
}

// ---- weight packing into MFMA B-fragment order -----------------------------
// wp[(s*4+t)*64 + l] holds 8 bf16: B[k=32s + (l>>4)*8 + j][c=16t + (l&15)]
// Weight split: k-steps 0,1 (xi operand) get Wd = W1[:64]-W1[64:]; k-steps
// 2,3 (xj operand) get Wb = W1[64:]. Then no xj-xi subtraction is needed.
__global__ void pack_w(const float* __restrict__ W1, const float* __restrict__ W2,
                       short* __restrict__ wp1, short* __restrict__ wp2) {
  int tid = blockIdx.x * blockDim.x + threadIdx.x;
  if (tid < 1024) {
    int l = tid & 63, st = tid >> 6;
    int s = st >> 2, t = st & 3;
    int quad = l >> 4, n16 = l & 15;
    for (int j = 0; j < 8; j++) {
      int k = 32 * s + quad * 8 + j, c = 16 * t + n16;
      float w = (s < 2) ? (W1[k * 64 + c] - W1[(k + 64) * 64 + c])
                        : W1[k * 64 + c];
      wp1[tid * 8 + j] = bf16b(w);
    }
  } else if (tid < 1536) {
    int e = tid - 1024;
    int l = e & 63, st = e >> 6;
    int s = st >> 2, t = st & 3;
    int quad = l >> 4, n16 = l & 15;
    for (int j = 0; j < 8; j++) {
      int k = 32 * s + quad * 8 + j, c = 16 * t + n16;
      wp2[e * 8 + j] = bf16b(W2[k * 64 + c]);
    }
  }
}

// ---- stats helpers ---------------------------------------------------------
static __device__ __forceinline__ void stat_acc(const f32x4 acc[4], float sacc[4],
                                                float qacc[4]) {
#pragma unroll
  for (int t = 0; t < 4; t++) {
    sacc[t] += (acc[t][0] + acc[t][1]) + (acc[t][2] + acc[t][3]);
    qacc[t] = fmaf(acc[t][0], acc[t][0],
              fmaf(acc[t][1], acc[t][1],
              fmaf(acc[t][2], acc[t][2],
              fmaf(acc[t][3], acc[t][3], qacc[t]))));
  }
}

static __device__ __forceinline__ void stat_flush(float sacc[4], float qacc[4],
                                                  int quad, int n16, float* lstat) {
#pragma unroll
  for (int t = 0; t < 4; t++) {
    float s = sacc[t], q = qacc[t];
    s += __shfl_xor(s, 16); s += __shfl_xor(s, 32);
    q += __shfl_xor(q, 16); q += __shfl_xor(q, 32);
    if (quad == 0) {
      atomicAdd(&lstat[16 * t + n16], s);
      atomicAdd(&lstat[64 + 16 * t + n16], q);
    }
  }
}

// ---- pass 1: 4-nodes-per-wave gather + GEMM1 + stats1 ----------------------
__global__ __launch_bounds__(256, 4) void k_pass1(const short* __restrict__ xb,
                                                  const int* __restrict__ ecol,
                                                  const bf16x8* __restrict__ wp1,
                                                  float* __restrict__ gacc) {
  __shared__ float lstat[128];
  __shared__ int eblk[256];
  __shared__ __align__(16) short xit[1024];     // 16 xi rows (2 KB)
  __shared__ __align__(16) short wfl[8192];     // W1 B-frags (16 KB)
  int tid = threadIdx.x;
  if (tid < 128) lstat[tid] = 0.f;
  int nb = blockIdx.x * 16;
  eblk[tid] = ecol[nb * KE + tid];              // 256 indices, coalesced
  if (tid < 128)
    *(bf16x8*)(&xit[tid * 8]) = ((const bf16x8*)(xb + (size_t)nb * 64))[tid];
#pragma unroll
  for (int r = 0; r < 4; r++)                   // 16 KB W1 frags -> LDS
    ((bf16x8*)wfl)[r * 256 + tid] = wp1[r * 256 + tid];
  __syncthreads();
  int wave = tid >> 6, l = tid & 63, quad = l >> 4, n16 = l & 15;
  const bf16x8* wf = (const bf16x8*)wfl;
  // all 8 gather loads up-front: 4 nodes x 2 x 16B per lane, static regs
  bf16x8 j0[4], j1[4];
#pragma unroll
  for (int v = 0; v < 4; v++) {
    int idx = eblk[(wave * 4 + v) * 16 + n16];
    const short* pj = xb + (size_t)idx * 64 + quad * 8;
    j0[v] = *(const bf16x8*)pj;
    j1[v] = *(const bf16x8*)(pj + 32);
  }
  float sacc[4] = {0.f, 0.f, 0.f, 0.f}, qacc[4] = {0.f, 0.f, 0.f, 0.f};
#pragma unroll
  for (int v = 0; v < 4; v++) {
    int p = wave * 4 + v;
    bf16x8 xi0 = *(const bf16x8*)(&xit[p * 64 + quad * 8]);
    bf16x8 xi1 = *(const bf16x8*)(&xit[p * 64 + 32 + quad * 8]);
    f32x4 acc[4];
#pragma unroll
    for (int t = 0; t < 4; t++) {
      f32x4 a = {0.f, 0.f, 0.f, 0.f};
      a = MFMA(xi0, wf[(0 + t) * 64 + l], a);
      a = MFMA(xi1, wf[(4 + t) * 64 + l], a);
      a = MFMA(j0[v], wf[(8 + t) * 64 + l], a);
      a = MFMA(j1[v], wf[(12 + t) * 64 + l], a);
      acc[t] = a;
    }
    stat_acc(acc, sacc, qacc);
  }
  stat_flush(sacc, qacc, quad, n16, lstat);
  __syncthreads();
  if (tid < 128) atomicAdd(&gacc[(blockIdx.x & 63) * 128 + tid], lstat[tid]);
}

// ---- BN stats finalize -----------------------------------------------------
__global__ void k_finalize(const float* __restrict__ gacc, const float* __restrict__ g,
                           const float* __restrict__ be, float* __restrict__ bn) {
  int c = threadIdx.x;  // 64 threads
  float s = 0.f, q = 0.f;
  for (int i = 0; i < 64; i++) {
    s += gacc[i * 128 + c];
    q += gacc[i * 128 + 64 + c];
  }
  float mean = s * (1.0f / E_EDGES);
  float var = q * (1.0f / E_EDGES) - mean * mean;  // biased, matches reference
  float rstd = rsqrtf(var + BN_EPS);
  float a = g[c] * rstd;
  bn[c] = a;
  bn[64 + c] = be[c] - mean * a;  // bn(v) = v*a + b
}

// ---- pass 2: gather + GEMM1 + BN1/ReLU + GEMM2 + stats2 + node min/max -----
__global__ __launch_bounds__(256, 3) void k_pass2(const short* __restrict__ xb,
                                                  const int* __restrict__ ecol,
                                                  const bf16x8* __restrict__ wp1,
                                                  const bf16x8* __restrict__ wp2,
                                                  const float* __restrict__ bn1,
                                                  float* __restrict__ gacc,
                                                  short* __restrict__ hmax,
                                                  short* __restrict__ hmin) {
  __shared__ float lstat[128];
  __shared__ int eblk[256];
  __shared__ __align__(16) short xit[1024];
  __shared__ __align__(16) short wfl[8192];          // W1 B-frags (16 KB)
  __shared__ __align__(16) short tiles[4][16 * 72];  // per-wave D->A transpose
  int tid = threadIdx.x;
  if (tid < 128) lstat[tid] = 0.f;
  int nb = blockIdx.x * 16;
  eblk[tid] = ecol[nb * KE + tid];
  if (tid < 128)
    *(bf16x8*)(&xit[tid * 8]) = ((const bf16x8*)(xb + (size_t)nb * 64))[tid];
#pragma unroll
  for (int r = 0; r < 4; r++)
    ((bf16x8*)wfl)[r * 256 + tid] = wp1[r * 256 + tid];
  __syncthreads();
  int wave = tid >> 6, l = tid & 63, quad = l >> 4, n16 = l & 15;
  const bf16x8* wf = (const bf16x8*)wfl;
  bf16x8 wf2[8];
#pragma unroll
  for (int u = 0; u < 8; u++) wf2[u] = wp2[u * 64 + l];
  float a1c[4], b1c[4];
#pragma unroll
  for (int t = 0; t < 4; t++) {
    a1c[t] = bn1[16 * t + n16];
    b1c[t] = bn1[64 + 16 * t + n16];
  }
  bf16x8 j0[4], j1[4];
#pragma unroll
  for (int v = 0; v < 4; v++) {
    int idx = eblk[(wave * 4 + v) * 16 + n16];
    const short* pj = xb + (size_t)idx * 64 + quad * 8;
    j0[v] = *(const bf16x8*)pj;
    j1[v] = *(const bf16x8*)(pj + 32);
  }
  float sacc[4] = {0.f, 0.f, 0.f, 0.f}, qacc[4] = {0.f, 0.f, 0.f, 0.f};
  short* myt = &tiles[wave][0];
#pragma unroll
  for (int v = 0; v < 4; v++) {
    int p = wave * 4 + v;
    bf16x8 xi0 = *(const bf16x8*)(&xit[p * 64 + quad * 8]);
    bf16x8 xi1 = *(const bf16x8*)(&xit[p * 64 + 32 + quad * 8]);
    f32x4 acc1[4];
#pragma unroll
    for (int t = 0; t < 4; t++) {
      f32x4 a = {0.f, 0.f, 0.f, 0.f};
      a = MFMA(xi0, wf[(0 + t) * 64 + l], a);
      a = MFMA(xi1, wf[(4 + t) * 64 + l], a);
      a = MFMA(j0[v], wf[(8 + t) * 64 + l], a);
      a = MFMA(j1[v], wf[(12 + t) * 64 + l], a);
      acc1[t] = a;
    }
    // BN1 + ReLU, D-layout -> row-major bf16 tile (per-wave, no barrier)
#pragma unroll
    for (int t = 0; t < 4; t++) {
      int c = 16 * t + n16;
#pragma unroll
      for (int r = 0; r < 4; r++) {
        float h = fmaxf(fmaf(acc1[t][r], a1c[t], b1c[t]), 0.f);
        myt[(quad * 4 + r) * 72 + c] = bf16b(h);
      }
    }
    bf16x8 f0 = *(bf16x8*)(myt + n16 * 72 + quad * 8);
    bf16x8 f1 = *(bf16x8*)(myt + n16 * 72 + 32 + quad * 8);
    f32x4 acc2[4];
#pragma unroll
    for (int t = 0; t < 4; t++) {
      f32x4 a = {0.f, 0.f, 0.f, 0.f};
      a = MFMA(f0, wf2[0 + t], a);
      a = MFMA(f1, wf2[4 + t], a);
      acc2[t] = a;
    }
    stat_acc(acc2, sacc, qacc);
    // per-node, per-channel max & min of h2_pre over the 16 edges
    float vmx[4], vmn[4];
#pragma unroll
    for (int t = 0; t < 4; t++) {
      float mx = fmaxf(fmaxf(acc2[t][0], acc2[t][1]), fmaxf(acc2[t][2], acc2[t][3]));
      float mn = fminf(fminf(acc2[t][0], acc2[t][1]), fminf(acc2[t][2], acc2[t][3]));
      mx = fmaxf(mx, __shfl_xor(mx, 16)); mx = fmaxf(mx, __shfl_xor(mx, 32));
      mn = fminf(mn, __shfl_xor(mn, 16)); mn = fminf(mn, __shfl_xor(mn, 32));
      vmx[t] = mx; vmn[t] = mn;
    }
    int n = nb + p;
    float ox = (quad == 0) ? vmx[0] : (quad == 1) ? vmx[1] : (quad == 2) ? vmx[2] : vmx[3];
    float on = (quad == 0) ? vmn[0] : (quad == 1) ? vmn[1] : (quad == 2) ? vmn[2] : vmn[3];
    hmax[(size_t)n * 64 + l] = bf16b(ox);  // lane l == channel l: coalesced
    hmin[(size_t)n * 64 + l] = bf16b(on);
  }
  stat_flush(sacc, qacc, quad, n16, lstat);
  __syncthreads();
  if (tid < 128) atomicAdd(&gacc[(blockIdx.x & 63) * 128 + tid], lstat[tid]);
}

// ---- pass 3: elementwise BN2 + ReLU + sign-select of stored min/max --------
// max_m relu(a*h+b) = relu(a>=0 ? a*hmax+b : a*hmin+b)  (affine+relu monotone)
__global__ __launch_bounds__(256) void k_pass3(const short* __restrict__ hmax,
                                               const short* __restrict__ hmin,
                                               const float* __restrict__ bn2,
                                               float* __restrict__ out) {
  int g = blockIdx.x * 256 + threadIdx.x;  // 1.6M threads, 4 channels each
  int base = g * 4;
  int c4 = base & 63;
  short4 mx4 = *(const short4*)(hmax + base);
  short4 mn4 = *(const short4*)(hmin + base);
  float4 a4 = *(const float4*)(bn2 + c4);
  float4 b4 = *(const float4*)(bn2 + 64 + c4);
  float4 o;
  o.x = fmaxf(a4.x >= 0.f ? fmaf(a4.x, bf2f(mx4.x), b4.x) : fmaf(a4.x, bf2f(mn4.x), b4.x), 0.f);
  o.y = fmaxf(a4.y >= 0.f ? fmaf(a4.y, bf2f(mx4.y), b4.y) : fmaf(a4.y, bf2f(mn4.y), b4.y), 0.f);
  o.z = fmaxf(a4.z >= 0.f ? fmaf(a4.z, bf2f(mx4.z), b4.z) : fmaf(a4.z, bf2f(mn4.z), b4.z), 0.f);
  o.w = fmaxf(a4.w >= 0.f ? fmaf(a4.w, bf2f(mx4.w), b4.w) : fmaf(a4.w, bf2f(mn4.w), b4.w), 0.f);
  *(float4*)(out + base) = o;
}

extern "C" void kernel_launch(void* const* d_in, const int* in_sizes, int n_in,
                              void* d_out, int out_size, void* d_ws, size_t ws_size,
                              hipStream_t stream) {
  const float* x   = (const float*)d_in[0];
  // d_in[1] = edge_row: structurally repeat(arange(N),16), unused
  const int*   ec  = (const int*)d_in[2];
  const float* W1  = (const float*)d_in[3];
  // d_in[4] = b1: cancels in BN, unused
  const float* g1  = (const float*)d_in[5];
  const float* be1 = (const float*)d_in[6];
  const float* W2  = (const float*)d_in[7];
  // d_in[8] = b2: cancels in BN, unused
  const float* g2  = (const float*)d_in[9];
  const float* be2 = (const float*)d_in[10];
  float* out = (float*)d_out;

  char* ws = (char*)d_ws;
  bf16x8* wp1  = (bf16x8*)(ws);                 // 16 KB packed W1 (split)
  bf16x8* wp2  = (bf16x8*)(ws + 16384);         // 8 KB packed W2
  float* gacc1 = (float*)(ws + 24576);          // 64 slots x 128 = 32 KB
  float* gacc2 = (float*)(ws + 57344);          // 32 KB
  float* bn1   = (float*)(ws + 90112);          // a[64], b[64]
  float* bn2   = (float*)(ws + 90624);
  short* xb    = (short*)(ws + 98304);          // x in bf16: 12.8 MB
  short* hmax  = (short*)(ws + 98304 + 12800000);         // 12.8 MB
  short* hmin  = (short*)(ws + 98304 + 2 * 12800000);     // 12.8 MB

  // ws is re-poisoned to 0xAA before every launch: zero the stat accumulators
  hipMemsetAsync(gacc1, 0, 65536, stream);

  hipLaunchKernelGGL(pack_w, dim3(6), dim3(256), 0, stream, W1, W2,
                     (short*)wp1, (short*)wp2);
  hipLaunchKernelGGL(k_cvt, dim3(3125), dim3(256), 0, stream, x, xb);
  hipLaunchKernelGGL(k_pass1, dim3(NCHUNK), dim3(256), 0, stream,
                     xb, ec, wp1, gacc1);
  hipLaunchKernelGGL(k_finalize, dim3(1), dim3(64), 0, stream, gacc1, g1, be1, bn1);
  hipLaunchKernelGGL(k_pass2, dim3(NCHUNK), dim3(256), 0, stream,
                     xb, ec, wp1, wp2, bn1, gacc2, hmax, hmin);
  hipLaunchKernelGGL(k_finalize, dim3(1), dim3(64), 0, stream, gacc2, g2, be2, bn2);
  hipLaunchKernelGGL(k_pass3, dim3(6250), dim3(256), 0, stream, hmax, hmin, bn2, out);
}